// Round 3
// baseline (1028.867 us; speedup 1.0000x reference)
//
#include <hip/hip_runtime.h>
#include <cstdint>
#include <vector>
#include <algorithm>
#include <utility>

// ---------------- problem constants ----------------
#define BN 8
#define TN 16
#define HN 512
#define WN 512
#define HWN (HN*WN)          // 262144
#define HARDN 10
#define EASYN 29
#define NSEL 39
#define NBIN 4096
#define CAP 8192             // candidate cap per row (power of two, 64KB LDS)

// ---------------- ws layout (bytes) ----------------
static const size_t LS_OFF   = 0;                                  // float[BN][HWN]
static const size_t HIST_OFF = LS_OFF + (size_t)BN*HWN*4;          // uint[BN][NBIN]
static const size_t CCNT_OFF = HIST_OFF + (size_t)BN*NBIN*4;       // uint[BN] (pad 64)
static const size_t CAND_OFF = CCNT_OFF + 64;                      // u64[BN][CAP]
static const size_t SEL_OFF  = CAND_OFF + (size_t)BN*CAP*8;        // int[BN][64]
static const size_t ACC_OFF  = SEL_OFF + (size_t)BN*64*4;          // double (8-aligned)

struct SelConst { int idxpos[HARDN]; int easy[BN][EASYN]; };

// ---------------- host-side JAX threefry replication ----------------
// 1 = modern JAX (jax_threefry_partitionable=True default, >=0.4.36);
// 0 = legacy path. If validation is consistently ~1e-5 relative off, flip this.
#define JAX_PARTITIONABLE 1

static inline void tf2x32(uint32_t k0, uint32_t k1, uint32_t& x0, uint32_t& x1) {
  uint32_t ks0 = k0, ks1 = k1, ks2 = k0 ^ k1 ^ 0x1BD11BDAu;
  uint32_t v0 = x0 + ks0, v1 = x1 + ks1;
  static const int r0[4] = {13,15,26,6}, r1[4] = {17,29,16,24};
  uint32_t ks[3] = {ks0, ks1, ks2};
  for (int i = 0; i < 5; ++i) {
    const int* rot = (i & 1) ? r1 : r0;
    for (int j = 0; j < 4; ++j) {
      v0 += v1;
      v1 = (v1 << rot[j]) | (v1 >> (32 - rot[j]));
      v1 ^= v0;
    }
    v0 += ks[(i + 1) % 3];
    v1 += ks[(i + 2) % 3] + (uint32_t)(i + 1);
  }
  x0 = v0; x1 = v1;
}

// jax.random.split(key, num) -> out[2*j], out[2*j+1] = key_j
static void jax_split(uint32_t k0, uint32_t k1, int num, uint32_t* out) {
#if JAX_PARTITIONABLE
  // foldlike: counter = 64-bit iota -> (hi=0, lo=j)
  for (int j = 0; j < num; ++j) {
    uint32_t a = 0, b = (uint32_t)j;
    tf2x32(k0, k1, a, b);
    out[2*j] = a; out[2*j+1] = b;
  }
#else
  // original: counts = iota(2*num) split in halves; out = concat(v0,v1).reshape(num,2)
  int h = num;
  std::vector<uint32_t> o(2*num);
  for (int i = 0; i < h; ++i) {
    uint32_t a = (uint32_t)i, b = (uint32_t)(i + h);
    tf2x32(k0, k1, a, b);
    o[i] = a; o[i+h] = b;
  }
  for (int i = 0; i < 2*num; ++i) out[i] = o[i];
#endif
}

// random_bits(key, 32, (n,)), n even
static void jax_bits(uint32_t k0, uint32_t k1, uint32_t n, std::vector<uint32_t>& bits) {
  bits.resize(n);
#if JAX_PARTITIONABLE
  for (uint32_t i = 0; i < n; ++i) {
    uint32_t a = 0, b = i;
    tf2x32(k0, k1, a, b);
    bits[i] = a ^ b;      // 32-bit partitionable path: hi ^ lo
  }
#else
  uint32_t h = n / 2;
  for (uint32_t i = 0; i < h; ++i) {
    uint32_t a = i, b = i + h;
    tf2x32(k0, k1, a, b);
    bits[i] = a; bits[i+h] = b;
  }
#endif
}

// jax._src.random._shuffle: per round: key,subkey=split(key); stable sort by bits
static void jax_shuffle(uint32_t k0, uint32_t k1, std::vector<uint32_t>& x, int rounds) {
  size_t n = x.size();
  std::vector<uint32_t> bits;
  std::vector<std::pair<uint64_t,uint32_t>> tmp(n);
  uint32_t ck0 = k0, ck1 = k1;
  for (int r = 0; r < rounds; ++r) {
    uint32_t sp[4];
    jax_split(ck0, ck1, 2, sp);
    ck0 = sp[0]; ck1 = sp[1];                    // key = keys[0]
    jax_bits(sp[2], sp[3], (uint32_t)n, bits);   // subkey = keys[1]
    for (size_t i = 0; i < n; ++i)
      tmp[i] = { ((uint64_t)bits[i] << 32) | (uint32_t)i, x[i] };  // (bits,pos) = stable
    std::sort(tmp.begin(), tmp.end(),
              [](const std::pair<uint64_t,uint32_t>& A,
                 const std::pair<uint64_t,uint32_t>& B){ return A.first < B.first; });
    for (size_t i = 0; i < n; ++i) x[i] = tmp[i].second;
  }
}

static SelConst build_sel() {
  SelConst sc;
  uint32_t root[4];
  jax_split(0u, 42u, 2, root);                 // key(42) = (0,42): k_idx, k_easy
  {
    std::vector<uint32_t> x(130);
    for (int i = 0; i < 130; ++i) x[i] = (uint32_t)i;
    jax_shuffle(root[0], root[1], x, 1);       // n=130 -> ceil(3*ln130/ln(2^32-1)) = 1 round
    for (int j = 0; j < HARDN; ++j) sc.idxpos[j] = (int)x[j] + 20;
  }
  uint32_t ek[2*BN];
  jax_split(root[2], root[3], BN, ek);
  for (int b = 0; b < BN; ++b) {
    std::vector<uint32_t> x(HWN);
    for (uint32_t i = 0; i < (uint32_t)HWN; ++i) x[i] = i;
    jax_shuffle(ek[2*b], ek[2*b+1], x, 2);     // n=262144 -> 2 rounds
    for (int j = 0; j < EASYN; ++j) sc.easy[b][j] = (int)x[j];
  }
  return sc;
}

// Computed at library-load time (before any kernel_launch): no per-call static
// guard, so every kernel_launch executes an identical instruction stream
// (graph-capture requirement).
static const SelConst g_sc = build_sel();

// ---------------- device ----------------
__device__ __forceinline__ void logsig(float xv, float& logpt, float& logptbk) {
  // jax.nn.log_sigmoid(x) = -(max(-x,0) + log1p(exp(-|x|)))
  float l1p = log1pf(expf(-fabsf(xv)));
  logpt   = -(fmaxf(-xv, 0.f) + l1p);
  logptbk = -(fmaxf( xv, 0.f) + l1p);
}

__global__ __launch_bounds__(256) void kInit(unsigned int* __restrict__ hist,
                                             unsigned int* __restrict__ ccnt,
                                             double* __restrict__ accum) {
  int i = blockIdx.x * 256 + threadIdx.x;
  if (i < BN*NBIN) hist[i] = 0u;
  if (i < BN) ccnt[i] = 0u;
  if (i == 0) *accum = 0.0;
}

// Dense pass: prot (5x5 OR via separable sums) + bce + sum over t
//             + pos focal term + loss_sum histogram
__global__ __launch_bounds__(256) void kA(const float* __restrict__ x,
                                          const int* __restrict__ tgt,
                                          float* __restrict__ loss_sum,
                                          unsigned int* __restrict__ hist,
                                          double* __restrict__ accum) {
  const int tile = blockIdx.x;              // 0..63 (8x8 tiles of 64x64)
  const int b    = blockIdx.y;              // 0..7
  const int ty = (tile >> 3) << 6;
  const int tx = (tile & 7) << 6;
  const int tid = threadIdx.x;
  const int col = tid & 63;
  const int rr4 = tid >> 6;                 // 0..3

  __shared__ float s_tg[68*68];             // target tile + 2-halo (18496 B)
  __shared__ float s_h[68*64];              // horizontal 5-sum     (17408 B)
  __shared__ double s_pos[4];
  static_assert(sizeof(float)*68*68 >= sizeof(unsigned int)*NBIN, "shist alias fits");

  float lsum[16];
  #pragma unroll
  for (int p = 0; p < 16; ++p) lsum[p] = 0.f;
  double posA = 0.0;

  for (int t = 0; t < TN; ++t) {
    const size_t base = ((size_t)(b*TN + t)) << 18;   // *HWN
    const int*   tg = tgt + base;
    const float* xx = x   + base;
    __syncthreads();
    for (int i = tid; i < 68*68; i += 256) {
      int r = i / 68, c = i - r*68;
      int gy = ty + r - 2, gx = tx + c - 2;
      float v = 0.f;
      if ((unsigned)gy < (unsigned)HN && (unsigned)gx < (unsigned)WN)
        v = (float)tg[(gy << 9) + gx];
      s_tg[i] = v;
    }
    __syncthreads();
    for (int i = tid; i < 68*64; i += 256) {
      int r = i >> 6, c = i & 63;
      const float* row = s_tg + r*68 + c;
      s_h[i] = row[0] + row[1] + row[2] + row[3] + row[4];
    }
    __syncthreads();
    #pragma unroll
    for (int p = 0; p < 16; ++p) {
      int r = p*4 + rr4;
      int gy = ty + r, gx = tx + col;
      float pr = s_h[(r+0)*64+col] + s_h[(r+1)*64+col] + s_h[(r+2)*64+col]
               + s_h[(r+3)*64+col] + s_h[(r+4)*64+col];
      float tv = s_tg[(r+2)*68 + (col+2)];
      float xv = xx[(gy << 9) + gx];
      float logpt, logptbk;
      logsig(xv, logpt, logptbk);
      float bce = (tv > 0.f) ? -logpt : -logptbk;
      if (!(pr > 0.f)) lsum[p] += bce;       // loss_p = bce * (1 - prot)
      if (tv > 0.f) {                        // tgt=1 => wgt_new=1 always
        float pt = expf(logpt);
        float om = 1.f - pt;
        posA += (double)(-0.75f * om * om * logpt);
      }
    }
  }

  // write loss_sum tile
  float* ls = loss_sum + (((size_t)b) << 18);
  #pragma unroll
  for (int p = 0; p < 16; ++p) {
    int r = p*4 + rr4;
    ls[((ty + r) << 9) + tx + col] = lsum[p];
  }

  // histogram of float bits >> 19 (values >= 0 -> bits monotone, bin < 4096)
  unsigned int* shist = (unsigned int*)s_tg;
  __syncthreads();
  for (int i = tid; i < NBIN; i += 256) shist[i] = 0u;
  __syncthreads();
  #pragma unroll
  for (int p = 0; p < 16; ++p) {
    unsigned int vb = __float_as_uint(lsum[p]);
    atomicAdd(&shist[vb >> 19], 1u);
  }
  __syncthreads();
  unsigned int* gh = hist + (b << 12);
  for (int i = tid; i < NBIN; i += 256) {
    unsigned int c = shist[i];
    if (c) atomicAdd(&gh[i], c);
  }

  // reduce pos term (4 waves -> LDS -> one atomic)
  for (int off = 32; off > 0; off >>= 1) posA += __shfl_down(posA, off, 64);
  if ((tid & 63) == 0) s_pos[tid >> 6] = posA;
  __syncthreads();
  if (tid == 0) atomicAdd(accum, s_pos[0] + s_pos[1] + s_pos[2] + s_pos[3]);
}

// Collect top-K candidates: threshold bin from histogram, then atomic append
__global__ __launch_bounds__(256) void kCollect(const float* __restrict__ loss_sum,
                                                const unsigned int* __restrict__ hist,
                                                unsigned int* __restrict__ ccnt,
                                                unsigned long long* __restrict__ cand) {
  const int part = blockIdx.x;              // 0..15
  const int row  = blockIdx.y;              // 0..7
  const int tid  = threadIdx.x;
  __shared__ unsigned int s_chunk[256];
  __shared__ int s_thr;
  const unsigned int* gh = hist + (row << 12);
  unsigned int cs = 0;
  #pragma unroll
  for (int j = 0; j < 16; ++j) cs += gh[tid*16 + j];
  s_chunk[tid] = cs;
  __syncthreads();
  if (tid == 0) {
    // smallest bin thr such that |{v : bin(v) >= thr}| >= 200
    int thr = 0;
    unsigned int cum = 0;
    for (int c = 255; c >= 0; --c) {
      unsigned int cc = s_chunk[c];
      if (cum + cc >= 200u) {
        unsigned int cum2 = cum;
        int bin;
        for (bin = c*16 + 15; bin > c*16; --bin) {
          cum2 += gh[bin];
          if (cum2 >= 200u) break;
        }
        thr = bin;   // loop fall-through (bin==c*16) is the correct threshold
        break;
      }
      cum += cc;
    }
    s_thr = thr;
  }
  __syncthreads();
  const int thr = s_thr;
  const float* ls = loss_sum + (((size_t)row) << 18);
  unsigned long long* cr = cand + (((size_t)row) << 13);
  const int lo = part * (HWN/16), hi = lo + (HWN/16);
  for (int i = lo + tid; i < hi; i += 256) {
    unsigned int vb = __float_as_uint(ls[i]);
    if ((int)(vb >> 19) >= thr) {
      unsigned int pos = atomicAdd(&ccnt[row], 1u);
      if (pos < CAP)
        cr[pos] = (((unsigned long long)(~vb)) << 32) | (unsigned int)i;  // asc = desc val, asc idx
    }
  }
}

// Bitonic sort candidates, emit sel[row][0..38] (hard ranks + deduped easy)
__global__ __launch_bounds__(1024) void kSort(const unsigned long long* __restrict__ cand,
                                              const unsigned int* __restrict__ ccnt,
                                              int* __restrict__ sel, SelConst sc) {
  const int row = blockIdx.x;
  const int tid = threadIdx.x;
  __shared__ unsigned long long s_k[CAP];
  unsigned int n = ccnt[row]; if (n > CAP) n = CAP;
  const unsigned long long* cr = cand + (((size_t)row) << 13);
  for (int i = tid; i < CAP; i += 1024)
    s_k[i] = (i < (int)n) ? cr[i] : 0xFFFFFFFFFFFFFFFFULL;
  for (int k = 2; k <= CAP; k <<= 1) {
    for (int j = k >> 1; j > 0; j >>= 1) {
      __syncthreads();
      for (int i = tid; i < CAP; i += 1024) {
        int p = i ^ j;
        if (p > i) {
          unsigned long long a = s_k[i], b = s_k[p];
          bool up = ((i & k) == 0);
          if (up ? (a > b) : (a < b)) { s_k[i] = b; s_k[p] = a; }
        }
      }
    }
  }
  __syncthreads();
  if (tid < NSEL) {
    int v;
    if (tid < HARDN) {
      v = (int)(unsigned int)(s_k[sc.idxpos[tid]] & 0xFFFFFFFFULL);
    } else {
      int e = sc.easy[row][tid - HARDN];
      bool dup = false;
      #pragma unroll
      for (int j = 0; j < HARDN; ++j)
        dup |= ((int)(unsigned int)(s_k[sc.idxpos[j]] & 0xFFFFFFFFULL) == e);
      v = dup ? -1 : e;    // mask2d .set(1.0) is idempotent -> dedup easy vs hard
    }
    sel[row*64 + tid] = v;
  }
}

// Sparse neg pass: for each selected (b,hw), each t with tgt==0 && prot==0
__global__ __launch_bounds__(128) void kC(const float* __restrict__ x,
                                          const int* __restrict__ tgt,
                                          const int* __restrict__ sel,
                                          double* __restrict__ accum) {
  const int si  = blockIdx.x;               // 0..38
  const int row = blockIdx.y;               // 0..7
  const int p = sel[row*64 + si];
  if (p < 0) return;                        // deduped easy slot
  const int cy = p >> 9, cx = p & 511;
  const int tid = threadIdx.x;
  const int t = tid >> 3, sub = tid & 7;    // 8 lanes per t-slice
  const size_t base = ((size_t)(row*TN + t)) << 18;
  const int* tg = tgt + base;
  int protc = 0;
  for (int w = sub; w < 25; w += 8) {
    int dy = w / 5 - 2, dx = w % 5 - 2;
    int gy = cy + dy, gx = cx + dx;
    if ((unsigned)gy < (unsigned)HN && (unsigned)gx < (unsigned)WN)
      protc += tg[(gy << 9) + gx];
  }
  protc += __shfl_xor(protc, 1, 64);
  protc += __shfl_xor(protc, 2, 64);
  protc += __shfl_xor(protc, 4, 64);
  __shared__ double s_term[TN];
  if (sub == 0) {
    double term = 0.0;
    int tv = tg[(cy << 9) + cx];
    if (tv == 0 && protc == 0) {
      float xv = x[base + (size_t)((cy << 9) + cx)];
      float logpt, logptbk;
      logsig(xv, logpt, logptbk);
      float ptbk = 1.f - expf(logptbk);     // pt_bk = 1 - exp(log_sigmoid(-x))
      term = (double)(-0.25f * ptbk * ptbk * logptbk);
    }
    s_term[t] = term;
  }
  __syncthreads();
  if (tid == 0) {
    double s = 0.0;
    #pragma unroll
    for (int u = 0; u < TN; ++u) s += s_term[u];
    atomicAdd(accum, s);
  }
}

__global__ void kD(const double* __restrict__ accum, float* __restrict__ out) {
  out[0] = (float)(*accum);
}

// ---------------- launch ----------------
extern "C" void kernel_launch(void* const* d_in, const int* in_sizes, int n_in,
                              void* d_out, int out_size, void* d_ws, size_t ws_size,
                              hipStream_t stream) {
  const float* x   = (const float*)d_in[0];
  const int*   tgt = (const int*)d_in[1];
  float* out = (float*)d_out;
  char* ws = (char*)d_ws;
  float*              loss_sum = (float*)(ws + LS_OFF);
  unsigned int*       hist     = (unsigned int*)(ws + HIST_OFF);
  unsigned int*       ccnt     = (unsigned int*)(ws + CCNT_OFF);
  unsigned long long* cand     = (unsigned long long*)(ws + CAND_OFF);
  int*                sel      = (int*)(ws + SEL_OFF);
  double*             accum    = (double*)(ws + ACC_OFF);

  hipLaunchKernelGGL(kInit,    dim3((BN*NBIN + 255)/256), dim3(256), 0, stream, hist, ccnt, accum);
  hipLaunchKernelGGL(kA,       dim3(64, BN),  dim3(256),  0, stream, x, tgt, loss_sum, hist, accum);
  hipLaunchKernelGGL(kCollect, dim3(16, BN),  dim3(256),  0, stream, loss_sum, hist, ccnt, cand);
  hipLaunchKernelGGL(kSort,    dim3(BN),      dim3(1024), 0, stream, cand, ccnt, sel, g_sc);
  hipLaunchKernelGGL(kC,       dim3(NSEL, BN),dim3(128),  0, stream, x, tgt, sel, accum);
  hipLaunchKernelGGL(kD,       dim3(1),       dim3(1),    0, stream, accum, out);
}

// Round 4
// 528.845 us; speedup vs baseline: 1.9455x; 1.9455x over previous
//
#include <hip/hip_runtime.h>
#include <cstdint>
#include <vector>
#include <algorithm>
#include <utility>

// ---------------- problem constants ----------------
#define BN 8
#define TN 16
#define HN 512
#define WN 512
#define HWN (HN*WN)          // 262144
#define HARDN 10
#define EASYN 29
#define NSEL 39
#define NBIN 4096
#define CAP 2048             // candidate cap per row (power of two; realistic count ~few hundred)

typedef unsigned long long u64;

// ---------------- ws layout (bytes) ----------------
static const size_t LS_OFF   = 0;                                  // float[BN][HWN]
static const size_t HIST_OFF = LS_OFF + (size_t)BN*HWN*4;          // uint[BN][NBIN]
static const size_t CCNT_OFF = HIST_OFF + (size_t)BN*NBIN*4;       // uint[BN] (pad 64)
static const size_t CAND_OFF = CCNT_OFF + 64;                      // u64[BN][CAP]
static const size_t SEL_OFF  = CAND_OFF + (size_t)BN*CAP*8;        // int[BN][64]
static const size_t ACC_OFF  = SEL_OFF + (size_t)BN*64*4;          // double (8-aligned)

struct SelConst { int idxpos[HARDN]; int easy[BN][EASYN]; };

// ---------------- host-side JAX threefry replication (verified bit-exact r3) --
#define JAX_PARTITIONABLE 1

static inline void tf2x32(uint32_t k0, uint32_t k1, uint32_t& x0, uint32_t& x1) {
  uint32_t ks0 = k0, ks1 = k1, ks2 = k0 ^ k1 ^ 0x1BD11BDAu;
  uint32_t v0 = x0 + ks0, v1 = x1 + ks1;
  static const int r0[4] = {13,15,26,6}, r1[4] = {17,29,16,24};
  uint32_t ks[3] = {ks0, ks1, ks2};
  for (int i = 0; i < 5; ++i) {
    const int* rot = (i & 1) ? r1 : r0;
    for (int j = 0; j < 4; ++j) {
      v0 += v1;
      v1 = (v1 << rot[j]) | (v1 >> (32 - rot[j]));
      v1 ^= v0;
    }
    v0 += ks[(i + 1) % 3];
    v1 += ks[(i + 2) % 3] + (uint32_t)(i + 1);
  }
  x0 = v0; x1 = v1;
}

static void jax_split(uint32_t k0, uint32_t k1, int num, uint32_t* out) {
#if JAX_PARTITIONABLE
  for (int j = 0; j < num; ++j) {
    uint32_t a = 0, b = (uint32_t)j;
    tf2x32(k0, k1, a, b);
    out[2*j] = a; out[2*j+1] = b;
  }
#else
  int h = num;
  std::vector<uint32_t> o(2*num);
  for (int i = 0; i < h; ++i) {
    uint32_t a = (uint32_t)i, b = (uint32_t)(i + h);
    tf2x32(k0, k1, a, b);
    o[i] = a; o[i+h] = b;
  }
  for (int i = 0; i < 2*num; ++i) out[i] = o[i];
#endif
}

static void jax_bits(uint32_t k0, uint32_t k1, uint32_t n, std::vector<uint32_t>& bits) {
  bits.resize(n);
#if JAX_PARTITIONABLE
  for (uint32_t i = 0; i < n; ++i) {
    uint32_t a = 0, b = i;
    tf2x32(k0, k1, a, b);
    bits[i] = a ^ b;
  }
#else
  uint32_t h = n / 2;
  for (uint32_t i = 0; i < h; ++i) {
    uint32_t a = i, b = i + h;
    tf2x32(k0, k1, a, b);
    bits[i] = a; bits[i+h] = b;
  }
#endif
}

static void jax_shuffle(uint32_t k0, uint32_t k1, std::vector<uint32_t>& x, int rounds) {
  size_t n = x.size();
  std::vector<uint32_t> bits;
  std::vector<std::pair<uint64_t,uint32_t>> tmp(n);
  uint32_t ck0 = k0, ck1 = k1;
  for (int r = 0; r < rounds; ++r) {
    uint32_t sp[4];
    jax_split(ck0, ck1, 2, sp);
    ck0 = sp[0]; ck1 = sp[1];
    jax_bits(sp[2], sp[3], (uint32_t)n, bits);
    for (size_t i = 0; i < n; ++i)
      tmp[i] = { ((uint64_t)bits[i] << 32) | (uint32_t)i, x[i] };
    std::sort(tmp.begin(), tmp.end(),
              [](const std::pair<uint64_t,uint32_t>& A,
                 const std::pair<uint64_t,uint32_t>& B){ return A.first < B.first; });
    for (size_t i = 0; i < n; ++i) x[i] = tmp[i].second;
  }
}

static SelConst build_sel() {
  SelConst sc;
  uint32_t root[4];
  jax_split(0u, 42u, 2, root);
  {
    std::vector<uint32_t> x(130);
    for (int i = 0; i < 130; ++i) x[i] = (uint32_t)i;
    jax_shuffle(root[0], root[1], x, 1);
    for (int j = 0; j < HARDN; ++j) sc.idxpos[j] = (int)x[j] + 20;
  }
  uint32_t ek[2*BN];
  jax_split(root[2], root[3], BN, ek);
  for (int b = 0; b < BN; ++b) {
    std::vector<uint32_t> x(HWN);
    for (uint32_t i = 0; i < (uint32_t)HWN; ++i) x[i] = i;
    jax_shuffle(ek[2*b], ek[2*b+1], x, 2);
    for (int j = 0; j < EASYN; ++j) sc.easy[b][j] = (int)x[j];
  }
  return sc;
}

// Library-load-time constant: no per-call static guard (graph-capture safe).
static const SelConst g_sc = build_sel();

// ---------------- device ----------------
__device__ __forceinline__ void logsig(float xv, float& logpt, float& logptbk) {
  // jax.nn.log_sigmoid(x) = -(max(-x,0) + log1p(exp(-|x|)))  [bit-exact match]
  float l1p = log1pf(expf(-fabsf(xv)));
  logpt   = -(fmaxf(-xv, 0.f) + l1p);
  logptbk = -(fmaxf( xv, 0.f) + l1p);
}

__global__ __launch_bounds__(256) void kInit(unsigned int* __restrict__ hist,
                                             unsigned int* __restrict__ ccnt,
                                             double* __restrict__ accum) {
  int i = blockIdx.x * 256 + threadIdx.x;
  if (i < BN*NBIN) hist[i] = 0u;
  if (i < BN) ccnt[i] = 0u;
  if (i == 0) *accum = 0.0;
}

// Dense pass, bitmask edition.
// prot is a 5x5 binary OR of a 0/1 image -> per halo-row build a 64-bit ballot
// mask m and its horizontal 5-window OR H (u64 ops), then per pixel
// prot = bit c of (H[r]|H[r+1]|H[r+2]|H[r+3]|H[r+4]).  LDS = 2x(M,H)[68] u64
// double-buffered (2.2 KB) -> broadcast reads, zero bank conflicts.
// 1024 threads/block (16 waves), 512 blocks = 2 blocks/CU, 1 barrier per t.
__global__ __launch_bounds__(1024) void kA(const float* __restrict__ x,
                                           const int* __restrict__ tgt,
                                           float* __restrict__ loss_sum,
                                           unsigned int* __restrict__ hist,
                                           double* __restrict__ accum) {
  const int tile = blockIdx.x;              // 0..63 (8x8 tiles of 64x64)
  const int b    = blockIdx.y;              // 0..7
  const int ty = (tile >> 3) << 6;
  const int tx = (tile & 7) << 6;
  const int tid = threadIdx.x;
  const int c = tid & 63;                   // lane = column
  const int w = tid >> 6;                   // wave 0..15

  __shared__ u64 Mbuf[2][68];               // center masks (halo rows)
  __shared__ u64 Hbuf[2][68];               // horizontal 5-OR masks
  __shared__ unsigned int shist[NBIN];
  __shared__ double s_pos[16];

  for (int i = tid; i < NBIN; i += 1024) shist[i] = 0u;

  float lsum[4] = {0.f, 0.f, 0.f, 0.f};
  double posA = 0.0;

  // phase1: build M/H for all 68 halo rows of time-slice T into parity buffer PB
#define PHASE1(T, PB) do {                                                      \
    const int* tg_ = tgt + (((size_t)(b*TN + (T))) << 18);                      \
    for (int r = w; r < 68; r += 16) {                                          \
      int gy = ty + r - 2; int tv = 0, hv = 0;                                  \
      if ((unsigned)gy < (unsigned)HN) {                                        \
        const int* rowp = tg_ + (gy << 9);                                      \
        tv = rowp[tx + c];                                                      \
        if (c < 2)        { int gx = tx - 2 + c; if (gx >= 0) hv = rowp[gx]; }  \
        else if (c >= 62) { int gx = tx + 2 + c; if (gx < WN) hv = rowp[gx]; }  \
      }                                                                         \
      u64 mb = __ballot(tv > 0);                                                \
      u64 hb = __ballot(hv > 0);                                                \
      /* 68-bit window bits: lo=cols tx-2..tx+61, hi=cols tx+62..tx+65 */       \
      u64 lo = (hb & 3ull) | (mb << 2);                                         \
      u64 hi = (mb >> 62) | (((hb >> 62) & 3ull) << 2);                         \
      u64 Hv = lo | (lo >> 1) | (lo >> 2) | (lo >> 3) | (lo >> 4)               \
                  | (hi << 63) | (hi << 62) | (hi << 61) | (hi << 60);          \
      if (c == 0) { Mbuf[PB][r] = mb; Hbuf[PB][r] = Hv; }                       \
    }                                                                           \
  } while (0)

  PHASE1(0, 0);
  __syncthreads();

  for (int t = 0; t < TN; ++t) {
    const int pb = t & 1;
    // phase2: wave w computes tile rows 4w..4w+3 (needs halo rows 4w..4w+7)
    {
      const float* xx = x + (((size_t)(b*TN + t)) << 18);
      const int rb = 4 * w;
      u64 h0 = Hbuf[pb][rb+0], h1 = Hbuf[pb][rb+1], h2 = Hbuf[pb][rb+2],
          h3 = Hbuf[pb][rb+3], h4 = Hbuf[pb][rb+4], h5 = Hbuf[pb][rb+5],
          h6 = Hbuf[pb][rb+6], h7 = Hbuf[pb][rb+7];
      u64 t23 = h2 | h3, t45 = h4 | h5;
      u64 Ps[4];
      Ps[0] = h0 | h1 | t23 | h4;
      Ps[1] = h1 | t23 | t45;
      Ps[2] = t23 | t45 | h6;
      Ps[3] = h3 | t45 | h6 | h7;
      u64 Ms[4] = {Mbuf[pb][rb+2], Mbuf[pb][rb+3], Mbuf[pb][rb+4], Mbuf[pb][rb+5]};
      #pragma unroll
      for (int i = 0; i < 4; ++i) {
        float xv = xx[((ty + rb + i) << 9) + tx + c];
        float logpt, logptbk;
        logsig(xv, logpt, logptbk);
        unsigned tvb   = (unsigned)((Ms[i] >> c) & 1ull);
        unsigned protb = (unsigned)((Ps[i] >> c) & 1ull);
        float bce = tvb ? -logpt : -logptbk;
        if (!protb) lsum[i] += bce;          // loss_p = bce * (1 - prot)
        if (tvb) {                           // tgt=1 => wgt_new=1 always
          float pt = expf(logpt);
          float om = 1.f - pt;
          posA += (double)(-0.75f * om * om * logpt);
        }
      }
    }
    if (t + 1 < TN) PHASE1(t + 1, (t + 1) & 1);
    __syncthreads();
  }
#undef PHASE1

  // write loss_sum tile (coalesced per row)
  float* ls = loss_sum + (((size_t)b) << 18);
  #pragma unroll
  for (int i = 0; i < 4; ++i)
    ls[((ty + 4*w + i) << 9) + tx + c] = lsum[i];

  // histogram of float bits >> 19 (values >= 0 -> bits monotone, bin < 4096)
  #pragma unroll
  for (int i = 0; i < 4; ++i)
    atomicAdd(&shist[__float_as_uint(lsum[i]) >> 19], 1u);

  // pos reduce: wave shfl -> LDS
  for (int off = 32; off > 0; off >>= 1) posA += __shfl_down(posA, off, 64);
  if (c == 0) s_pos[w] = posA;
  __syncthreads();

  unsigned int* gh = hist + (b << 12);
  for (int i = tid; i < NBIN; i += 1024) {
    unsigned int cc = shist[i];
    if (cc) atomicAdd(&gh[i], cc);
  }
  if (tid == 0) {
    double s = 0.0;
    #pragma unroll
    for (int u = 0; u < 16; ++u) s += s_pos[u];
    atomicAdd(accum, s);
  }
}

// Collect top-K candidates: threshold bin from histogram, then atomic append
__global__ __launch_bounds__(256) void kCollect(const float* __restrict__ loss_sum,
                                                const unsigned int* __restrict__ hist,
                                                unsigned int* __restrict__ ccnt,
                                                unsigned long long* __restrict__ cand) {
  const int part = blockIdx.x;              // 0..63
  const int row  = blockIdx.y;              // 0..7
  const int tid  = threadIdx.x;
  __shared__ unsigned int s_chunk[256];
  __shared__ int s_thr;
  const unsigned int* gh = hist + (row << 12);
  unsigned int cs = 0;
  #pragma unroll
  for (int j = 0; j < 16; ++j) cs += gh[tid*16 + j];
  s_chunk[tid] = cs;
  __syncthreads();
  if (tid == 0) {
    // smallest bin thr such that |{v : bin(v) >= thr}| >= 200
    int thr = 0;
    unsigned int cum = 0;
    for (int c = 255; c >= 0; --c) {
      unsigned int cc = s_chunk[c];
      if (cum + cc >= 200u) {
        unsigned int cum2 = cum;
        int bin;
        for (bin = c*16 + 15; bin > c*16; --bin) {
          cum2 += gh[bin];
          if (cum2 >= 200u) break;
        }
        thr = bin;
        break;
      }
      cum += cc;
    }
    s_thr = thr;
  }
  __syncthreads();
  const int thr = s_thr;
  const float* ls = loss_sum + (((size_t)row) << 18);
  unsigned long long* cr = cand + (size_t)row * CAP;
  const int lo = part * (HWN/64), hi = lo + (HWN/64);
  for (int i = lo + tid; i < hi; i += 256) {
    unsigned int vb = __float_as_uint(ls[i]);
    if ((int)(vb >> 19) >= thr) {
      unsigned int pos = atomicAdd(&ccnt[row], 1u);
      if (pos < CAP)
        cr[pos] = (((unsigned long long)(~vb)) << 32) | (unsigned int)i;  // asc = desc val, asc idx
    }
  }
}

// Bitonic sort candidates, emit sel[row][0..38] (hard ranks + deduped easy)
__global__ __launch_bounds__(1024) void kSort(const unsigned long long* __restrict__ cand,
                                              const unsigned int* __restrict__ ccnt,
                                              int* __restrict__ sel, SelConst sc) {
  const int row = blockIdx.x;
  const int tid = threadIdx.x;
  __shared__ unsigned long long s_k[CAP];
  unsigned int n = ccnt[row]; if (n > CAP) n = CAP;
  const unsigned long long* cr = cand + (size_t)row * CAP;
  for (int i = tid; i < CAP; i += 1024)
    s_k[i] = (i < (int)n) ? cr[i] : 0xFFFFFFFFFFFFFFFFULL;
  for (int k = 2; k <= CAP; k <<= 1) {
    for (int j = k >> 1; j > 0; j >>= 1) {
      __syncthreads();
      for (int i = tid; i < CAP; i += 1024) {
        int p = i ^ j;
        if (p > i) {
          unsigned long long a = s_k[i], bb = s_k[p];
          bool up = ((i & k) == 0);
          if (up ? (a > bb) : (a < bb)) { s_k[i] = bb; s_k[p] = a; }
        }
      }
    }
  }
  __syncthreads();
  if (tid < NSEL) {
    int v;
    if (tid < HARDN) {
      v = (int)(unsigned int)(s_k[sc.idxpos[tid]] & 0xFFFFFFFFULL);
    } else {
      int e = sc.easy[row][tid - HARDN];
      bool dup = false;
      #pragma unroll
      for (int j = 0; j < HARDN; ++j)
        dup |= ((int)(unsigned int)(s_k[sc.idxpos[j]] & 0xFFFFFFFFULL) == e);
      v = dup ? -1 : e;    // mask2d .set(1.0) idempotent -> dedup easy vs hard
    }
    sel[row*64 + tid] = v;
  }
}

// Sparse neg pass: for each selected (b,hw), each t with tgt==0 && prot==0
__global__ __launch_bounds__(128) void kC(const float* __restrict__ x,
                                          const int* __restrict__ tgt,
                                          const int* __restrict__ sel,
                                          double* __restrict__ accum) {
  const int si  = blockIdx.x;               // 0..38
  const int row = blockIdx.y;               // 0..7
  const int p = sel[row*64 + si];
  if (p < 0) return;                        // deduped easy slot
  const int cy = p >> 9, cx = p & 511;
  const int tid = threadIdx.x;
  const int t = tid >> 3, sub = tid & 7;    // 8 lanes per t-slice
  const size_t base = ((size_t)(row*TN + t)) << 18;
  const int* tg = tgt + base;
  int protc = 0;
  for (int w = sub; w < 25; w += 8) {
    int dy = w / 5 - 2, dx = w % 5 - 2;
    int gy = cy + dy, gx = cx + dx;
    if ((unsigned)gy < (unsigned)HN && (unsigned)gx < (unsigned)WN)
      protc += tg[(gy << 9) + gx];
  }
  protc += __shfl_xor(protc, 1, 64);
  protc += __shfl_xor(protc, 2, 64);
  protc += __shfl_xor(protc, 4, 64);
  __shared__ double s_term[TN];
  if (sub == 0) {
    double term = 0.0;
    int tv = tg[(cy << 9) + cx];
    if (tv == 0 && protc == 0) {
      float xv = x[base + (size_t)((cy << 9) + cx)];
      float logpt, logptbk;
      logsig(xv, logpt, logptbk);
      float ptbk = 1.f - expf(logptbk);
      term = (double)(-0.25f * ptbk * ptbk * logptbk);
    }
    s_term[t] = term;
  }
  __syncthreads();
  if (tid == 0) {
    double s = 0.0;
    #pragma unroll
    for (int u = 0; u < TN; ++u) s += s_term[u];
    atomicAdd(accum, s);
  }
}

__global__ void kD(const double* __restrict__ accum, float* __restrict__ out) {
  out[0] = (float)(*accum);
}

// ---------------- launch ----------------
extern "C" void kernel_launch(void* const* d_in, const int* in_sizes, int n_in,
                              void* d_out, int out_size, void* d_ws, size_t ws_size,
                              hipStream_t stream) {
  const float* x   = (const float*)d_in[0];
  const int*   tgt = (const int*)d_in[1];
  float* out = (float*)d_out;
  char* ws = (char*)d_ws;
  float*              loss_sum = (float*)(ws + LS_OFF);
  unsigned int*       hist     = (unsigned int*)(ws + HIST_OFF);
  unsigned int*       ccnt     = (unsigned int*)(ws + CCNT_OFF);
  unsigned long long* cand     = (unsigned long long*)(ws + CAND_OFF);
  int*                sel      = (int*)(ws + SEL_OFF);
  double*             accum    = (double*)(ws + ACC_OFF);

  hipLaunchKernelGGL(kInit,    dim3((BN*NBIN + 255)/256), dim3(256), 0, stream, hist, ccnt, accum);
  hipLaunchKernelGGL(kA,       dim3(64, BN),  dim3(1024), 0, stream, x, tgt, loss_sum, hist, accum);
  hipLaunchKernelGGL(kCollect, dim3(64, BN),  dim3(256),  0, stream, loss_sum, hist, ccnt, cand);
  hipLaunchKernelGGL(kSort,    dim3(BN),      dim3(1024), 0, stream, cand, ccnt, sel, g_sc);
  hipLaunchKernelGGL(kC,       dim3(NSEL, BN),dim3(128),  0, stream, x, tgt, sel, accum);
  hipLaunchKernelGGL(kD,       dim3(1),       dim3(1),    0, stream, accum, out);
}

// Round 7
// 475.349 us; speedup vs baseline: 2.1644x; 1.1125x over previous
//
#include <hip/hip_runtime.h>
#include <cstdint>
#include <vector>
#include <algorithm>
#include <utility>

// ---------------- problem constants ----------------
#define BN 8
#define TN 16
#define HN 512
#define WN 512
#define HWN (HN*WN)          // 262144
#define HARDN 10
#define EASYN 29
#define NSEL 39
#define NBIN 4096
#define CAP 2048             // candidate cap per row (realistic ~600; threshold-bin analysis)

typedef unsigned long long u64;

// ---------------- ws layout (bytes) ----------------
static const size_t LS_OFF   = 0;                                  // float[BN][HWN]
static const size_t HIST_OFF = LS_OFF + (size_t)BN*HWN*4;          // uint[BN][NBIN]
static const size_t CCNT_OFF = HIST_OFF + (size_t)BN*NBIN*4;       // uint[BN] (pad 64)
static const size_t CAND_OFF = CCNT_OFF + 64;                      // u64[BN][CAP]
static const size_t SEL_OFF  = CAND_OFF + (size_t)BN*CAP*8;        // int[BN][64]
static const size_t ACC_OFF  = SEL_OFF + (size_t)BN*64*4;          // double (8-aligned)

struct SelConst { int idxpos[HARDN]; int easy[BN][EASYN]; };

// ---------------- host-side JAX threefry replication (bit-exact, verified r3/r4) --
#define JAX_PARTITIONABLE 1

static inline void tf2x32(uint32_t k0, uint32_t k1, uint32_t& x0, uint32_t& x1) {
  uint32_t ks0 = k0, ks1 = k1, ks2 = k0 ^ k1 ^ 0x1BD11BDAu;
  uint32_t v0 = x0 + ks0, v1 = x1 + ks1;
  static const int r0[4] = {13,15,26,6}, r1[4] = {17,29,16,24};
  uint32_t ks[3] = {ks0, ks1, ks2};
  for (int i = 0; i < 5; ++i) {
    const int* rot = (i & 1) ? r1 : r0;
    for (int j = 0; j < 4; ++j) {
      v0 += v1;
      v1 = (v1 << rot[j]) | (v1 >> (32 - rot[j]));
      v1 ^= v0;
    }
    v0 += ks[(i + 1) % 3];
    v1 += ks[(i + 2) % 3] + (uint32_t)(i + 1);
  }
  x0 = v0; x1 = v1;
}

static void jax_split(uint32_t k0, uint32_t k1, int num, uint32_t* out) {
#if JAX_PARTITIONABLE
  for (int j = 0; j < num; ++j) {
    uint32_t a = 0, b = (uint32_t)j;
    tf2x32(k0, k1, a, b);
    out[2*j] = a; out[2*j+1] = b;
  }
#else
  int h = num;
  std::vector<uint32_t> o(2*num);
  for (int i = 0; i < h; ++i) {
    uint32_t a = (uint32_t)i, b = (uint32_t)(i + h);
    tf2x32(k0, k1, a, b);
    o[i] = a; o[i+h] = b;
  }
  for (int i = 0; i < 2*num; ++i) out[i] = o[i];
#endif
}

static void jax_bits(uint32_t k0, uint32_t k1, uint32_t n, std::vector<uint32_t>& bits) {
  bits.resize(n);
#if JAX_PARTITIONABLE
  for (uint32_t i = 0; i < n; ++i) {
    uint32_t a = 0, b = i;
    tf2x32(k0, k1, a, b);
    bits[i] = a ^ b;
  }
#else
  uint32_t h = n / 2;
  for (uint32_t i = 0; i < h; ++i) {
    uint32_t a = i, b = i + h;
    tf2x32(k0, k1, a, b);
    bits[i] = a; bits[i+h] = b;
  }
#endif
}

static void jax_shuffle(uint32_t k0, uint32_t k1, std::vector<uint32_t>& x, int rounds) {
  size_t n = x.size();
  std::vector<uint32_t> bits;
  std::vector<std::pair<uint64_t,uint32_t>> tmp(n);
  uint32_t ck0 = k0, ck1 = k1;
  for (int r = 0; r < rounds; ++r) {
    uint32_t sp[4];
    jax_split(ck0, ck1, 2, sp);
    ck0 = sp[0]; ck1 = sp[1];
    jax_bits(sp[2], sp[3], (uint32_t)n, bits);
    for (size_t i = 0; i < n; ++i)
      tmp[i] = { ((uint64_t)bits[i] << 32) | (uint32_t)i, x[i] };
    std::sort(tmp.begin(), tmp.end(),
              [](const std::pair<uint64_t,uint32_t>& A,
                 const std::pair<uint64_t,uint32_t>& B){ return A.first < B.first; });
    for (size_t i = 0; i < n; ++i) x[i] = tmp[i].second;
  }
}

static SelConst build_sel() {
  SelConst sc;
  uint32_t root[4];
  jax_split(0u, 42u, 2, root);
  {
    std::vector<uint32_t> x(130);
    for (int i = 0; i < 130; ++i) x[i] = (uint32_t)i;
    jax_shuffle(root[0], root[1], x, 1);
    for (int j = 0; j < HARDN; ++j) sc.idxpos[j] = (int)x[j] + 20;
  }
  uint32_t ek[2*BN];
  jax_split(root[2], root[3], BN, ek);
  for (int b = 0; b < BN; ++b) {
    std::vector<uint32_t> x(HWN);
    for (uint32_t i = 0; i < (uint32_t)HWN; ++i) x[i] = i;
    jax_shuffle(ek[2*b], ek[2*b+1], x, 2);
    for (int j = 0; j < EASYN; ++j) sc.easy[b][j] = (int)x[j];
  }
  return sc;
}

// Library-load-time constant: no per-call static guard (graph-capture safe).
static const SelConst g_sc = build_sel();

// ---------------- device ----------------
__global__ __launch_bounds__(256) void kInit(unsigned int* __restrict__ hist,
                                             unsigned int* __restrict__ ccnt,
                                             double* __restrict__ accum) {
  int i = blockIdx.x * 256 + threadIdx.x;
  if (i < BN*NBIN) hist[i] = 0u;
  if (i < BN) ccnt[i] = 0u;
  if (i == 0) *accum = 0.0;
}

// Dense pass, bitmask prot, 64x16 tiles, 256 threads (4 waves), 2048 blocks.
// LDS = double-buffered row masks only (~700B) -> 8 blocks/CU.
__global__ __launch_bounds__(256) void kA(const float* __restrict__ x,
                                          const int* __restrict__ tgt,
                                          float* __restrict__ loss_sum,
                                          double* __restrict__ accum) {
  const int tile = blockIdx.x;              // 0..255: (row-tile 0..31) x (col-tile 0..7)
  const int b    = blockIdx.y;              // 0..7
  const int ty = (tile >> 3) << 4;          // 32 row-tiles of 16 rows
  const int tx = (tile & 7) << 6;           // 8 col-tiles of 64 cols
  const int tid = threadIdx.x;
  const int c = tid & 63;                   // lane = column
  const int w = tid >> 6;                   // wave 0..3

  __shared__ u64 Mbuf[2][20];               // center masks (halo rows ty-2..ty+17)
  __shared__ u64 Hbuf[2][20];               // horizontal 5-OR masks
  __shared__ double s_pos[4];

  float lsum[4] = {0.f, 0.f, 0.f, 0.f};
  double posA = 0.0;

  // phase1: build M/H for the 20 halo rows of time-slice T into parity buffer PB
#define PHASE1(T, PB) do {                                                      \
    const int* tg_ = tgt + (((size_t)(b*TN + (T))) << 18);                      \
    for (int r = w; r < 20; r += 4) {                                           \
      int gy = ty + r - 2; int tv = 0, hv = 0;                                  \
      if ((unsigned)gy < (unsigned)HN) {                                        \
        const int* rowp = tg_ + (gy << 9);                                      \
        tv = rowp[tx + c];                                                      \
        if (c < 2)        { int gx = tx - 2 + c; if (gx >= 0) hv = rowp[gx]; }  \
        else if (c >= 62) { int gx = tx + 2 + c; if (gx < WN) hv = rowp[gx]; }  \
      }                                                                         \
      u64 mb = __ballot(tv > 0);                                                \
      u64 hb = __ballot(hv > 0);                                                \
      /* 68-bit window bits: lo=cols tx-2..tx+61, hi=cols tx+62..tx+65 */       \
      u64 lo = (hb & 3ull) | (mb << 2);                                         \
      u64 hi = (mb >> 62) | (((hb >> 62) & 3ull) << 2);                         \
      u64 Hv = lo | (lo >> 1) | (lo >> 2) | (lo >> 3) | (lo >> 4)               \
                  | (hi << 63) | (hi << 62) | (hi << 61) | (hi << 60);          \
      if (c == 0) { Mbuf[PB][r] = mb; Hbuf[PB][r] = Hv; }                       \
    }                                                                           \
  } while (0)

  PHASE1(0, 0);
  __syncthreads();

  for (int t = 0; t < TN; ++t) {
    const int pb = t & 1;
    {
      const float* xx = x + (((size_t)(b*TN + t)) << 18);
      const int rb = 4 * w;                 // wave w owns tile rows rb..rb+3
      u64 h0 = Hbuf[pb][rb+0], h1 = Hbuf[pb][rb+1], h2 = Hbuf[pb][rb+2],
          h3 = Hbuf[pb][rb+3], h4 = Hbuf[pb][rb+4], h5 = Hbuf[pb][rb+5],
          h6 = Hbuf[pb][rb+6], h7 = Hbuf[pb][rb+7];
      u64 t23 = h2 | h3, t45 = h4 | h5;
      u64 Ps[4];
      Ps[0] = h0 | h1 | t23 | h4;
      Ps[1] = h1 | t23 | t45;
      Ps[2] = t23 | t45 | h6;
      Ps[3] = h3 | t45 | h6 | h7;
      u64 Ms[4] = {Mbuf[pb][rb+2], Mbuf[pb][rb+3], Mbuf[pb][rb+4], Mbuf[pb][rb+5]};
      #pragma unroll
      for (int i = 0; i < 4; ++i) {
        float xv = xx[((ty + rb + i) << 9) + tx + c];
        unsigned tvb   = (unsigned)((Ms[i] >> c) & 1ull);
        unsigned protb = (unsigned)((Ps[i] >> c) & 1ull);
        // bce = tv ? -log_sigmoid(x) : -log_sigmoid(-x)
        //     = fmax(tv ? -x : x, 0) + log1p(exp(-|x|))   [bit-identical]
        float l1p = log1pf(expf(-fabsf(xv)));
        float bce = fmaxf(tvb ? -xv : xv, 0.f) + l1p;
        if (!protb) lsum[i] += bce;          // loss_p = bce * (1 - prot)
        if (Ms[i]) {                         // wave-uniform skip: no positives in segment
          if (tvb) {                         // tgt=1 => wgt_new=1 always
            float logpt = -bce;              // when tvb, bce == -logpt
            float pt = expf(logpt);
            float om = 1.f - pt;
            posA += (double)(-0.75f * om * om * logpt);
          }
        }
      }
    }
    if (t + 1 < TN) PHASE1(t + 1, (t + 1) & 1);
    __syncthreads();
  }
#undef PHASE1

  // write loss_sum tile (coalesced per row)
  float* ls = loss_sum + (((size_t)b) << 18);
  {
    const int rb = 4 * w;
    #pragma unroll
    for (int i = 0; i < 4; ++i)
      ls[((ty + rb + i) << 9) + tx + c] = lsum[i];
  }

  // pos reduce: wave shfl -> LDS -> one atomic
  for (int off = 32; off > 0; off >>= 1) posA += __shfl_down(posA, off, 64);
  if (c == 0) s_pos[w] = posA;
  __syncthreads();
  if (tid == 0)
    atomicAdd(accum, s_pos[0] + s_pos[1] + s_pos[2] + s_pos[3]);
}

// Histogram of loss_sum float bits >> 19 (values >= 0 -> bits monotone, bin < 4096)
__global__ __launch_bounds__(256) void kHist(const float* __restrict__ loss_sum,
                                             unsigned int* __restrict__ hist) {
  const int part = blockIdx.x;              // 0..63
  const int row  = blockIdx.y;              // 0..7
  const int tid  = threadIdx.x;
  __shared__ unsigned int sh[NBIN];
  for (int i = tid; i < NBIN; i += 256) sh[i] = 0u;
  __syncthreads();
  const float4* ls4 = (const float4*)(loss_sum + (((size_t)row) << 18) + part*(HWN/64));
  #pragma unroll
  for (int i = 0; i < 4; ++i) {             // 4096 floats per block = 4 float4/thread
    float4 v = ls4[tid + 256*i];
    atomicAdd(&sh[__float_as_uint(v.x) >> 19], 1u);
    atomicAdd(&sh[__float_as_uint(v.y) >> 19], 1u);
    atomicAdd(&sh[__float_as_uint(v.z) >> 19], 1u);
    atomicAdd(&sh[__float_as_uint(v.w) >> 19], 1u);
  }
  __syncthreads();
  unsigned int* gh = hist + (row << 12);
  for (int i = tid; i < NBIN; i += 256) {
    unsigned int cc = sh[i];
    if (cc) atomicAdd(&gh[i], cc);
  }
}

// Collect top-K candidates: threshold bin from histogram, then atomic append
__global__ __launch_bounds__(256) void kCollect(const float* __restrict__ loss_sum,
                                                const unsigned int* __restrict__ hist,
                                                unsigned int* __restrict__ ccnt,
                                                unsigned long long* __restrict__ cand) {
  const int part = blockIdx.x;              // 0..63
  const int row  = blockIdx.y;              // 0..7
  const int tid  = threadIdx.x;
  __shared__ unsigned int s_chunk[256];
  __shared__ int s_thr;
  const unsigned int* gh = hist + (row << 12);
  unsigned int cs = 0;
  #pragma unroll
  for (int j = 0; j < 16; ++j) cs += gh[tid*16 + j];
  s_chunk[tid] = cs;
  __syncthreads();
  if (tid == 0) {
    // smallest bin thr such that |{v : bin(v) >= thr}| >= 200
    int thr = 0;
    unsigned int cum = 0;
    for (int c = 255; c >= 0; --c) {
      unsigned int cc = s_chunk[c];
      if (cum + cc >= 200u) {
        unsigned int cum2 = cum;
        int bin;
        for (bin = c*16 + 15; bin > c*16; --bin) {
          cum2 += gh[bin];
          if (cum2 >= 200u) break;
        }
        thr = bin;
        break;
      }
      cum += cc;
    }
    s_thr = thr;
  }
  __syncthreads();
  const int thr = s_thr;
  const float* ls = loss_sum + (((size_t)row) << 18);
  unsigned long long* cr = cand + (size_t)row * CAP;
  const int lo = part * (HWN/64), hi = lo + (HWN/64);
  for (int i = lo + tid; i < hi; i += 256) {
    unsigned int vb = __float_as_uint(ls[i]);
    if ((int)(vb >> 19) >= thr) {
      unsigned int pos = atomicAdd(&ccnt[row], 1u);
      if (pos < CAP)
        cr[pos] = (((unsigned long long)(~vb)) << 32) | (unsigned int)i;  // asc = desc val, asc idx
    }
  }
}

// Counting-rank selection (replaces bitonic sort): rank = #keys smaller.
// Keys unique (valbits||index); candidates are a superset of the top-200 and
// all candidates outrank all non-candidates, so candidate-rank == global rank.
__global__ __launch_bounds__(1024) void kSelect(const unsigned long long* __restrict__ cand,
                                                const unsigned int* __restrict__ ccnt,
                                                int* __restrict__ sel, SelConst sc) {
  const int row = blockIdx.x;
  const int tid = threadIdx.x;
  __shared__ u64 s_k[CAP];
  __shared__ int s_hard[HARDN];
  unsigned int nu = ccnt[row]; if (nu > CAP) nu = CAP;
  const int n = (int)nu;
  const u64* cr = cand + (size_t)row * CAP;
  for (int i = tid; i < n; i += 1024) s_k[i] = cr[i];
  __syncthreads();
  for (int ci = tid; ci < n; ci += 1024) {
    u64 my = s_k[ci];
    int rank = 0;
    for (int j = 0; j < n; ++j) rank += (s_k[j] < my) ? 1 : 0;   // broadcast LDS read
    #pragma unroll
    for (int h = 0; h < HARDN; ++h)
      if (rank == sc.idxpos[h]) s_hard[h] = (int)(unsigned int)(my & 0xFFFFFFFFULL);
  }
  __syncthreads();
  if (tid < NSEL) {
    int v;
    if (tid < HARDN) {
      v = s_hard[tid];
    } else {
      int e = sc.easy[row][tid - HARDN];
      bool dup = false;
      #pragma unroll
      for (int j = 0; j < HARDN; ++j) dup |= (s_hard[j] == e);
      v = dup ? -1 : e;    // mask2d .set(1.0) idempotent -> dedup easy vs hard
    }
    sel[row*64 + tid] = v;
  }
}

// Sparse neg pass: for each selected (b,hw), each t with tgt==0 && prot==0
__global__ __launch_bounds__(128) void kC(const float* __restrict__ x,
                                          const int* __restrict__ tgt,
                                          const int* __restrict__ sel,
                                          double* __restrict__ accum) {
  const int si  = blockIdx.x;               // 0..38
  const int row = blockIdx.y;               // 0..7
  const int p = sel[row*64 + si];
  if (p < 0) return;                        // deduped easy slot
  const int cy = p >> 9, cx = p & 511;
  const int tid = threadIdx.x;
  const int t = tid >> 3, sub = tid & 7;    // 8 lanes per t-slice
  const size_t base = ((size_t)(row*TN + t)) << 18;
  const int* tg = tgt + base;
  int protc = 0;
  for (int w = sub; w < 25; w += 8) {
    int dy = w / 5 - 2, dx = w % 5 - 2;
    int gy = cy + dy, gx = cx + dx;
    if ((unsigned)gy < (unsigned)HN && (unsigned)gx < (unsigned)WN)
      protc += tg[(gy << 9) + gx];
  }
  protc += __shfl_xor(protc, 1, 64);
  protc += __shfl_xor(protc, 2, 64);
  protc += __shfl_xor(protc, 4, 64);
  __shared__ double s_term[TN];
  if (sub == 0) {
    double term = 0.0;
    int tv = tg[(cy << 9) + cx];
    if (tv == 0 && protc == 0) {
      float xv = x[base + (size_t)((cy << 9) + cx)];
      float l1p = log1pf(expf(-fabsf(xv)));
      float logptbk = -(fmaxf(xv, 0.f) + l1p);
      float ptbk = 1.f - expf(logptbk);
      term = (double)(-0.25f * ptbk * ptbk * logptbk);
    }
    s_term[t] = term;
  }
  __syncthreads();
  if (tid == 0) {
    double s = 0.0;
    #pragma unroll
    for (int u = 0; u < TN; ++u) s += s_term[u];
    atomicAdd(accum, s);
  }
}

__global__ void kD(const double* __restrict__ accum, float* __restrict__ out) {
  out[0] = (float)(*accum);
}

// ---------------- launch ----------------
extern "C" void kernel_launch(void* const* d_in, const int* in_sizes, int n_in,
                              void* d_out, int out_size, void* d_ws, size_t ws_size,
                              hipStream_t stream) {
  const float* x   = (const float*)d_in[0];
  const int*   tgt = (const int*)d_in[1];
  float* out = (float*)d_out;
  char* ws = (char*)d_ws;
  float*              loss_sum = (float*)(ws + LS_OFF);
  unsigned int*       hist     = (unsigned int*)(ws + HIST_OFF);
  unsigned int*       ccnt     = (unsigned int*)(ws + CCNT_OFF);
  unsigned long long* cand     = (unsigned long long*)(ws + CAND_OFF);
  int*                sel      = (int*)(ws + SEL_OFF);
  double*             accum    = (double*)(ws + ACC_OFF);

  hipLaunchKernelGGL(kInit,    dim3((BN*NBIN + 255)/256), dim3(256), 0, stream, hist, ccnt, accum);
  hipLaunchKernelGGL(kA,       dim3(256, BN), dim3(256),  0, stream, x, tgt, loss_sum, accum);
  hipLaunchKernelGGL(kHist,    dim3(64, BN),  dim3(256),  0, stream, loss_sum, hist);
  hipLaunchKernelGGL(kCollect, dim3(64, BN),  dim3(256),  0, stream, loss_sum, hist, ccnt, cand);
  hipLaunchKernelGGL(kSelect,  dim3(BN),      dim3(1024), 0, stream, cand, ccnt, sel, g_sc);
  hipLaunchKernelGGL(kC,       dim3(NSEL, BN),dim3(128),  0, stream, x, tgt, sel, accum);
  hipLaunchKernelGGL(kD,       dim3(1),       dim3(1),    0, stream, accum, out);
}

// Round 11
// 451.570 us; speedup vs baseline: 2.2784x; 1.0527x over previous
//
#include <hip/hip_runtime.h>
#include <cstdint>
#include <vector>
#include <algorithm>
#include <utility>

// ---------------- problem constants ----------------
#define BN 8
#define TN 16
#define HN 512
#define WN 512
#define HWN (HN*WN)          // 262144
#define HARDN 10
#define EASYN 29
#define NSEL 39
#define NBIN 4096
#define CAP 2048             // candidate cap per row (realistic ~600; threshold-bin analysis)

typedef unsigned long long u64;

// ---------------- ws layout (bytes) ----------------
static const size_t LS_OFF   = 0;                                  // float[BN][HWN]
static const size_t HIST_OFF = LS_OFF + (size_t)BN*HWN*4;          // uint[BN][NBIN]
static const size_t CCNT_OFF = HIST_OFF + (size_t)BN*NBIN*4;       // uint[BN] (pad 64)
static const size_t CAND_OFF = CCNT_OFF + 64;                      // u64[BN][CAP]
static const size_t SEL_OFF  = CAND_OFF + (size_t)BN*CAP*8;        // int[BN][64]
static const size_t ACC_OFF  = SEL_OFF + (size_t)BN*64*4;          // double (8-aligned)

struct SelConst { int idxpos[HARDN]; int easy[BN][EASYN]; };

// ---------------- host-side JAX threefry replication (bit-exact, verified r3/r4/r7) --
#define JAX_PARTITIONABLE 1

static inline void tf2x32(uint32_t k0, uint32_t k1, uint32_t& x0, uint32_t& x1) {
  uint32_t ks0 = k0, ks1 = k1, ks2 = k0 ^ k1 ^ 0x1BD11BDAu;
  uint32_t v0 = x0 + ks0, v1 = x1 + ks1;
  static const int r0[4] = {13,15,26,6}, r1[4] = {17,29,16,24};
  uint32_t ks[3] = {ks0, ks1, ks2};
  for (int i = 0; i < 5; ++i) {
    const int* rot = (i & 1) ? r1 : r0;
    for (int j = 0; j < 4; ++j) {
      v0 += v1;
      v1 = (v1 << rot[j]) | (v1 >> (32 - rot[j]));
      v1 ^= v0;
    }
    v0 += ks[(i + 1) % 3];
    v1 += ks[(i + 2) % 3] + (uint32_t)(i + 1);
  }
  x0 = v0; x1 = v1;
}

static void jax_split(uint32_t k0, uint32_t k1, int num, uint32_t* out) {
#if JAX_PARTITIONABLE
  for (int j = 0; j < num; ++j) {
    uint32_t a = 0, b = (uint32_t)j;
    tf2x32(k0, k1, a, b);
    out[2*j] = a; out[2*j+1] = b;
  }
#else
  int h = num;
  std::vector<uint32_t> o(2*num);
  for (int i = 0; i < h; ++i) {
    uint32_t a = (uint32_t)i, b = (uint32_t)(i + h);
    tf2x32(k0, k1, a, b);
    o[i] = a; o[i+h] = b;
  }
  for (int i = 0; i < 2*num; ++i) out[i] = o[i];
#endif
}

static void jax_bits(uint32_t k0, uint32_t k1, uint32_t n, std::vector<uint32_t>& bits) {
  bits.resize(n);
#if JAX_PARTITIONABLE
  for (uint32_t i = 0; i < n; ++i) {
    uint32_t a = 0, b = i;
    tf2x32(k0, k1, a, b);
    bits[i] = a ^ b;
  }
#else
  uint32_t h = n / 2;
  for (uint32_t i = 0; i < h; ++i) {
    uint32_t a = i, b = i + h;
    tf2x32(k0, k1, a, b);
    bits[i] = a; bits[i+h] = b;
  }
#endif
}

static void jax_shuffle(uint32_t k0, uint32_t k1, std::vector<uint32_t>& x, int rounds) {
  size_t n = x.size();
  std::vector<uint32_t> bits;
  std::vector<std::pair<uint64_t,uint32_t>> tmp(n);
  uint32_t ck0 = k0, ck1 = k1;
  for (int r = 0; r < rounds; ++r) {
    uint32_t sp[4];
    jax_split(ck0, ck1, 2, sp);
    ck0 = sp[0]; ck1 = sp[1];
    jax_bits(sp[2], sp[3], (uint32_t)n, bits);
    for (size_t i = 0; i < n; ++i)
      tmp[i] = { ((uint64_t)bits[i] << 32) | (uint32_t)i, x[i] };
    std::sort(tmp.begin(), tmp.end(),
              [](const std::pair<uint64_t,uint32_t>& A,
                 const std::pair<uint64_t,uint32_t>& B){ return A.first < B.first; });
    for (size_t i = 0; i < n; ++i) x[i] = tmp[i].second;
  }
}

static SelConst build_sel() {
  SelConst sc;
  uint32_t root[4];
  jax_split(0u, 42u, 2, root);
  {
    std::vector<uint32_t> x(130);
    for (int i = 0; i < 130; ++i) x[i] = (uint32_t)i;
    jax_shuffle(root[0], root[1], x, 1);
    for (int j = 0; j < HARDN; ++j) sc.idxpos[j] = (int)x[j] + 20;
  }
  uint32_t ek[2*BN];
  jax_split(root[2], root[3], BN, ek);
  for (int b = 0; b < BN; ++b) {
    std::vector<uint32_t> x(HWN);
    for (uint32_t i = 0; i < (uint32_t)HWN; ++i) x[i] = i;
    jax_shuffle(ek[2*b], ek[2*b+1], x, 2);
    for (int j = 0; j < EASYN; ++j) sc.easy[b][j] = (int)x[j];
  }
  return sc;
}

// Library-load-time constant: no per-call static guard (graph-capture safe).
static const SelConst g_sc = build_sel();

// ---------------- device ----------------
__global__ __launch_bounds__(256) void kInit(unsigned int* __restrict__ hist,
                                             unsigned int* __restrict__ ccnt,
                                             double* __restrict__ accum) {
  int i = blockIdx.x * 256 + threadIdx.x;
  if (i < BN*NBIN) hist[i] = 0u;
  if (i < BN) ccnt[i] = 0u;
  if (i == 0) *accum = 0.0;
}

// Dense pass, BARRIER-FREE t-loop. Each wave builds its own 8 halo-row masks
// via __ballot (masks live in SGPRs; 68-bit window math is scalar ALU).
// No __syncthreads in the main loop -> waves free-run; ~20 independent HBM
// loads in flight per wave per t; TLP hides latency.
// Histogram built from lsum registers with per-wave match-any aggregation
// (one LDS atomic per distinct bin per wave -> no same-address serialization).
__global__ __launch_bounds__(256) void kA(const float* __restrict__ x,
                                          const int* __restrict__ tgt,
                                          float* __restrict__ loss_sum,
                                          unsigned int* __restrict__ hist,
                                          double* __restrict__ accum) {
  const int tile = blockIdx.x;              // 0..255: (row-tile 0..31) x (col-tile 0..7)
  const int b    = blockIdx.y;              // 0..7
  const int ty = (tile >> 3) << 4;          // 32 row-tiles of 16 rows
  const int tx = (tile & 7) << 6;           // 8 col-tiles of 64 cols
  const int tid = threadIdx.x;
  const int c = tid & 63;                   // lane = column
  const int w = tid >> 6;                   // wave 0..3
  const int r0g = ty + 4*w - 2;             // global row of halo r=0 (wave-local)

  __shared__ unsigned int sh[NBIN];         // 16 KB -> 10 blocks/CU LDS-wise
  __shared__ double s_pos[4];

  for (int i = tid; i < NBIN; i += 256) sh[i] = 0u;
  __syncthreads();                          // barrier #1 (only 2 in whole kernel)

  float lsum[4] = {0.f, 0.f, 0.f, 0.f};
  double posA = 0.0;

  // per-lane halo column (constant over t,r): lanes 0,1 -> tx-2+c ; lanes 62,63 -> tx+2+c
  const int gxh = (c < 2) ? (tx - 2 + c) : ((c >= 62) ? (tx + 2 + c) : -1);
  const bool hvalid = ((unsigned)gxh < (unsigned)WN);

  for (int t = 0; t < TN; ++t) {
    const size_t base = ((size_t)(b*TN + t)) << 18;   // *HWN
    const int*   tg = tgt + base;
    const float* xx = x   + base;

    // issue all loads for this t up front (independent -> deep MLP)
    int tvv[8], hvv[8];
    #pragma unroll
    for (int r = 0; r < 8; ++r) {
      const int gy = r0g + r;
      const bool rv = ((unsigned)gy < (unsigned)HN);  // wave-uniform
      const int* rowp = tg + ((size_t)gy << 9);
      tvv[r] = rv ? rowp[tx + c] : 0;
      hvv[r] = (rv && hvalid) ? rowp[gxh] : 0;
    }
    float xv[4];
    #pragma unroll
    for (int i = 0; i < 4; ++i)
      xv[i] = xx[((size_t)(r0g + 2 + i) << 9) + tx + c];  // center rows always in-range

    // ballots -> wave-uniform (SGPR) masks; window math is scalar
    u64 m[8], H[8];
    #pragma unroll
    for (int r = 0; r < 8; ++r) {
      u64 mb = __ballot(tvv[r] > 0);
      u64 hb = __ballot(hvv[r] > 0);
      // 68-bit window bits: lo=cols tx-2..tx+61, hi=cols tx+62..tx+65
      u64 lo = (hb & 3ull) | (mb << 2);
      u64 hi = (mb >> 62) | (((hb >> 62) & 3ull) << 2);
      m[r] = mb;
      H[r] = lo | (lo >> 1) | (lo >> 2) | (lo >> 3) | (lo >> 4)
           | (hi << 63) | (hi << 62) | (hi << 61) | (hi << 60);
    }
    const u64 t23 = H[2] | H[3], t45 = H[4] | H[5];
    u64 Ps[4];
    Ps[0] = H[0] | H[1] | t23 | H[4];
    Ps[1] = H[1] | t23 | t45;
    Ps[2] = t23 | t45 | H[6];
    Ps[3] = H[3] | t45 | H[6] | H[7];

    #pragma unroll
    for (int i = 0; i < 4; ++i) {
      const float xvi = xv[i];
      const unsigned tvb   = (unsigned)((m[i+2] >> c) & 1ull);
      const unsigned protb = (unsigned)((Ps[i]  >> c) & 1ull);
      // bce = tv ? -log_sigmoid(x) : -log_sigmoid(-x)
      //     = fmax(tv ? -x : x, 0) + log1p(exp(-|x|))   [bit-identical to ref]
      const float l1p = log1pf(expf(-fabsf(xvi)));
      const float bce = fmaxf(tvb ? -xvi : xvi, 0.f) + l1p;
      if (!protb) lsum[i] += bce;            // loss_p = bce * (1 - prot)
      if (m[i+2]) {                          // wave-uniform (scalar branch) skip
        if (tvb) {                           // tgt=1 => wgt_new=1 always
          const float logpt = -bce;          // when tvb, bce == -logpt
          const float pt = expf(logpt);
          const float om = 1.f - pt;
          posA += (double)(-0.75f * om * om * logpt);
        }
      }
    }
  }

  // write loss_sum tile (coalesced per row)
  float* ls = loss_sum + (((size_t)b) << 18);
  #pragma unroll
  for (int i = 0; i < 4; ++i)
    ls[((size_t)(r0g + 2 + i) << 9) + tx + c] = lsum[i];

  // histogram from registers: per-wave match-any aggregation
  // (bin = float bits >> 19; lsum >= 0 finite -> bin <= 4079 < NBIN)
  #pragma unroll
  for (int i = 0; i < 4; ++i) {
    const unsigned bin = __float_as_uint(lsum[i]) >> 19;
    u64 active = ~0ull;                      // wave-uniform loop over distinct bins
    while (active) {
      const int lead = (int)(__ffsll((unsigned long long)active) - 1);
      const unsigned lbin = (unsigned)__shfl((int)bin, lead, 64);
      const u64 same = __ballot(bin == lbin);
      if (c == lead) atomicAdd(&sh[lbin], (unsigned)__popcll(same));
      active &= ~same;
    }
  }

  // pos reduce: wave shfl -> LDS
  for (int off = 32; off > 0; off >>= 1) posA += __shfl_down(posA, off, 64);
  if (c == 0) s_pos[w] = posA;
  __syncthreads();                          // barrier #2

  // flush histogram (only nonzero bins; <=1024 values/block so sparse)
  unsigned int* gh = hist + (b << 12);
  for (int i = tid; i < NBIN; i += 256) {
    const unsigned cc = sh[i];
    if (cc) atomicAdd(&gh[i], cc);
  }
  if (tid == 0)
    atomicAdd(accum, s_pos[0] + s_pos[1] + s_pos[2] + s_pos[3]);
}

// Collect top-K candidates: threshold bin from histogram, then atomic append
__global__ __launch_bounds__(256) void kCollect(const float* __restrict__ loss_sum,
                                                const unsigned int* __restrict__ hist,
                                                unsigned int* __restrict__ ccnt,
                                                unsigned long long* __restrict__ cand) {
  const int part = blockIdx.x;              // 0..63
  const int row  = blockIdx.y;              // 0..7
  const int tid  = threadIdx.x;
  __shared__ unsigned int s_chunk[256];
  __shared__ int s_thr;
  const unsigned int* gh = hist + (row << 12);
  unsigned int cs = 0;
  #pragma unroll
  for (int j = 0; j < 16; ++j) cs += gh[tid*16 + j];
  s_chunk[tid] = cs;
  __syncthreads();
  if (tid == 0) {
    // smallest bin thr such that |{v : bin(v) >= thr}| >= 200
    int thr = 0;
    unsigned int cum = 0;
    for (int c = 255; c >= 0; --c) {
      unsigned int cc = s_chunk[c];
      if (cum + cc >= 200u) {
        unsigned int cum2 = cum;
        int bin;
        for (bin = c*16 + 15; bin > c*16; --bin) {
          cum2 += gh[bin];
          if (cum2 >= 200u) break;
        }
        thr = bin;
        break;
      }
      cum += cc;
    }
    s_thr = thr;
  }
  __syncthreads();
  const int thr = s_thr;
  const float* ls = loss_sum + (((size_t)row) << 18);
  unsigned long long* cr = cand + (size_t)row * CAP;
  const int lo = part * (HWN/64), hi = lo + (HWN/64);
  for (int i = lo + tid; i < hi; i += 256) {
    unsigned int vb = __float_as_uint(ls[i]);
    if ((int)(vb >> 19) >= thr) {
      unsigned int pos = atomicAdd(&ccnt[row], 1u);
      if (pos < CAP)
        cr[pos] = (((unsigned long long)(~vb)) << 32) | (unsigned int)i;  // asc = desc val, asc idx
    }
  }
}

// Counting-rank selection: rank = #keys smaller. Keys unique (valbits||index);
// candidates are a superset of the top-200 and all candidates outrank all
// non-candidates, so candidate-rank == global rank (matches lax.top_k order).
__global__ __launch_bounds__(1024) void kSelect(const unsigned long long* __restrict__ cand,
                                                const unsigned int* __restrict__ ccnt,
                                                int* __restrict__ sel, SelConst sc) {
  const int row = blockIdx.x;
  const int tid = threadIdx.x;
  __shared__ u64 s_k[CAP];
  __shared__ int s_hard[HARDN];
  unsigned int nu = ccnt[row]; if (nu > CAP) nu = CAP;
  const int n = (int)nu;
  const u64* cr = cand + (size_t)row * CAP;
  for (int i = tid; i < n; i += 1024) s_k[i] = cr[i];
  __syncthreads();
  for (int ci = tid; ci < n; ci += 1024) {
    u64 my = s_k[ci];
    int rank = 0;
    for (int j = 0; j < n; ++j) rank += (s_k[j] < my) ? 1 : 0;   // broadcast LDS read
    #pragma unroll
    for (int h = 0; h < HARDN; ++h)
      if (rank == sc.idxpos[h]) s_hard[h] = (int)(unsigned int)(my & 0xFFFFFFFFULL);
  }
  __syncthreads();
  if (tid < NSEL) {
    int v;
    if (tid < HARDN) {
      v = s_hard[tid];
    } else {
      int e = sc.easy[row][tid - HARDN];
      bool dup = false;
      #pragma unroll
      for (int j = 0; j < HARDN; ++j) dup |= (s_hard[j] == e);
      v = dup ? -1 : e;    // mask2d .set(1.0) idempotent -> dedup easy vs hard
    }
    sel[row*64 + tid] = v;
  }
}

// Sparse neg pass: for each selected (b,hw), each t with tgt==0 && prot==0
__global__ __launch_bounds__(128) void kC(const float* __restrict__ x,
                                          const int* __restrict__ tgt,
                                          const int* __restrict__ sel,
                                          double* __restrict__ accum) {
  const int si  = blockIdx.x;               // 0..38
  const int row = blockIdx.y;               // 0..7
  const int p = sel[row*64 + si];
  if (p < 0) return;                        // deduped easy slot
  const int cy = p >> 9, cx = p & 511;
  const int tid = threadIdx.x;
  const int t = tid >> 3, sub = tid & 7;    // 8 lanes per t-slice
  const size_t base = ((size_t)(row*TN + t)) << 18;
  const int* tg = tgt + base;
  int protc = 0;
  for (int w = sub; w < 25; w += 8) {
    int dy = w / 5 - 2, dx = w % 5 - 2;
    int gy = cy + dy, gx = cx + dx;
    if ((unsigned)gy < (unsigned)HN && (unsigned)gx < (unsigned)WN)
      protc += tg[(gy << 9) + gx];
  }
  protc += __shfl_xor(protc, 1, 64);
  protc += __shfl_xor(protc, 2, 64);
  protc += __shfl_xor(protc, 4, 64);
  __shared__ double s_term[TN];
  if (sub == 0) {
    double term = 0.0;
    int tv = tg[(cy << 9) + cx];
    if (tv == 0 && protc == 0) {
      float xv = x[base + (size_t)((cy << 9) + cx)];
      float l1p = log1pf(expf(-fabsf(xv)));
      float logptbk = -(fmaxf(xv, 0.f) + l1p);
      float ptbk = 1.f - expf(logptbk);
      term = (double)(-0.25f * ptbk * ptbk * logptbk);
    }
    s_term[t] = term;
  }
  __syncthreads();
  if (tid == 0) {
    double s = 0.0;
    #pragma unroll
    for (int u = 0; u < TN; ++u) s += s_term[u];
    atomicAdd(accum, s);
  }
}

__global__ void kD(const double* __restrict__ accum, float* __restrict__ out) {
  out[0] = (float)(*accum);
}

// ---------------- launch ----------------
extern "C" void kernel_launch(void* const* d_in, const int* in_sizes, int n_in,
                              void* d_out, int out_size, void* d_ws, size_t ws_size,
                              hipStream_t stream) {
  const float* x   = (const float*)d_in[0];
  const int*   tgt = (const int*)d_in[1];
  float* out = (float*)d_out;
  char* ws = (char*)d_ws;
  float*              loss_sum = (float*)(ws + LS_OFF);
  unsigned int*       hist     = (unsigned int*)(ws + HIST_OFF);
  unsigned int*       ccnt     = (unsigned int*)(ws + CCNT_OFF);
  unsigned long long* cand     = (unsigned long long*)(ws + CAND_OFF);
  int*                sel      = (int*)(ws + SEL_OFF);
  double*             accum    = (double*)(ws + ACC_OFF);

  hipLaunchKernelGGL(kInit,    dim3((BN*NBIN + 255)/256), dim3(256), 0, stream, hist, ccnt, accum);
  hipLaunchKernelGGL(kA,       dim3(256, BN), dim3(256),  0, stream, x, tgt, loss_sum, hist, accum);
  hipLaunchKernelGGL(kCollect, dim3(64, BN),  dim3(256),  0, stream, loss_sum, hist, ccnt, cand);
  hipLaunchKernelGGL(kSelect,  dim3(BN),      dim3(1024), 0, stream, cand, ccnt, sel, g_sc);
  hipLaunchKernelGGL(kC,       dim3(NSEL, BN),dim3(128),  0, stream, x, tgt, sel, accum);
  hipLaunchKernelGGL(kD,       dim3(1),       dim3(1),    0, stream, accum, out);
}